// Round 1
// baseline (757.467 us; speedup 1.0000x reference)
//
#include <hip/hip_runtime.h>
#include <hip/hip_bf16.h>

typedef __hip_bfloat16 bf16;
typedef __attribute__((ext_vector_type(8))) short short8;
typedef __attribute__((ext_vector_type(4))) float f32x4;

#define T_TOK 6272
#define D_DIM 768
#define H_DIM 3072
#define NEXP 8
#define MAXTILES 160

__device__ __forceinline__ void async16(void* lds, const void* g) {
  __builtin_amdgcn_global_load_lds(
      (const __attribute__((address_space(1))) void*)g,
      (__attribute__((address_space(3))) void*)lds, 16, 0, 0);
}

// ---------------- small prep kernels ----------------

__global__ void cast_hilo(const float* __restrict__ in, bf16* __restrict__ hi,
                          bf16* __restrict__ lo, int n) {
  int i = blockIdx.x * blockDim.x + threadIdx.x;
  int stride = gridDim.x * blockDim.x;
  for (; i < n; i += stride) {
    float x = in[i];
    bf16 h = __float2bfloat16(x);
    hi[i] = h;
    lo[i] = __float2bfloat16(x - __bfloat162float(h));
  }
}

// in: [B][R][C] fp32 -> out: [B][C][R] bf16   (R,C multiples of 32)
__global__ void transpose_cast(const float* __restrict__ in, bf16* __restrict__ out,
                               int R, int C) {
  __shared__ float tile[32][33];
  int b = blockIdx.z;
  const float* ib = in + (size_t)b * R * C;
  bf16* ob = out + (size_t)b * R * C;
  int r0 = blockIdx.x * 32, c0 = blockIdx.y * 32;
  int tx = threadIdx.x & 31, ty = threadIdx.x >> 5;  // 32 x 8
  for (int i = 0; i < 32; i += 8)
    tile[ty + i][tx] = ib[(size_t)(r0 + ty + i) * C + c0 + tx];
  __syncthreads();
  for (int i = 0; i < 32; i += 8)
    ob[(size_t)(c0 + ty + i) * R + r0 + tx] = __float2bfloat16(tile[tx][ty + i]);
}

__global__ void norm_learnedE(const float* __restrict__ lE, float* __restrict__ eHat) {
  int wave = threadIdx.x >> 6, lane = threadIdx.x & 63;
  for (int e = wave; e < NEXP; e += 4) {
    float v[12];
    float ss = 0.f;
    for (int j = 0; j < 12; j++) {
      v[j] = lE[e * D_DIM + lane + 64 * j];
      ss += v[j] * v[j];
    }
    for (int o = 32; o; o >>= 1) ss += __shfl_xor(ss, o);
    float rn = 1.f / fmaxf(sqrtf(ss), 1e-12f);
    for (int j = 0; j < 12; j++) eHat[e * D_DIM + lane + 64 * j] = v[j] * rn;
  }
}

// ---------------- router GEMM (split-bf16, K' = 3*768 = 2304) ----------------
// y = patches @ Wlinear^T   (fp32-equivalent via Ah*Bh + Al*Bh + Ah*Bl)

__global__ __launch_bounds__(256) void gemm_router(
    const bf16* __restrict__ pHi, const bf16* __restrict__ pLo,
    const bf16* __restrict__ wHi, const bf16* __restrict__ wLo,
    float* __restrict__ y) {
  __shared__ __align__(16) bf16 As[128 * 32];
  __shared__ __align__(16) bf16 Bs[128 * 32];
  int tid = threadIdx.x, wave = tid >> 6, lane = tid & 63;
  int wr = wave >> 1, wc = wave & 1;
  int rowbase = blockIdx.x * 128, colbase = blockIdx.y * 128;
  int sc8 = (lane & 3) * 8;
  f32x4 acc[4][4];
  for (int m = 0; m < 4; m++)
    for (int n = 0; n < 4; n++) acc[m][n] = 0.f;

  for (int ks = 0; ks < 72; ks++) {
    int term = ks / 24;
    int kk = (ks % 24) * 32;
    const bf16* A = (term == 1) ? pLo : pHi;
    const bf16* B = (term == 2) ? wLo : wHi;
    __syncthreads();
    for (int p = 0; p < 2; p++) {
      int r = wave * 32 + p * 16 + (lane >> 2);
      async16(&As[(wave * 32 + p * 16) * 32], A + (size_t)(rowbase + r) * D_DIM + kk + sc8);
      async16(&Bs[(wave * 32 + p * 16) * 32], B + (size_t)(colbase + r) * D_DIM + kk + sc8);
    }
    __syncthreads();
    int koff = (lane >> 4) * 8;
    short8 af[4], bfr[4];
    for (int m = 0; m < 4; m++)
      af[m] = *(const short8*)&As[(wr * 64 + m * 16 + (lane & 15)) * 32 + koff];
    for (int n = 0; n < 4; n++)
      bfr[n] = *(const short8*)&Bs[(wc * 64 + n * 16 + (lane & 15)) * 32 + koff];
    for (int m = 0; m < 4; m++)
      for (int n = 0; n < 4; n++)
        acc[m][n] = __builtin_amdgcn_mfma_f32_16x16x32_bf16(af[m], bfr[n], acc[m][n], 0, 0, 0);
  }
  for (int m = 0; m < 4; m++)
    for (int n = 0; n < 4; n++)
      for (int j = 0; j < 4; j++) {
        int r = rowbase + wr * 64 + m * 16 + (lane >> 4) * 4 + j;
        int c = colbase + wc * 64 + n * 16 + (lane & 15);
        y[(size_t)r * D_DIM + c] = acc[m][n][j];
      }
}

// ---------------- router epilogue: l2norm + cosine + softmax + top2 ----------------

__global__ void router_epi(const float* __restrict__ y, const float* __restrict__ eHat,
                           const float* __restrict__ bias, int* __restrict__ gidx,
                           float* __restrict__ gval, int* __restrict__ counts) {
  int wave = threadIdx.x >> 6, lane = threadIdx.x & 63;
  int t = blockIdx.x * 4 + wave;
  float v[12];
  float ss = 0.f;
  for (int j = 0; j < 12; j++) {
    v[j] = y[(size_t)t * D_DIM + lane + 64 * j];
    ss += v[j] * v[j];
  }
  for (int o = 32; o; o >>= 1) ss += __shfl_xor(ss, o);
  float d[NEXP];
  for (int e = 0; e < NEXP; e++) {
    float s = 0.f;
    for (int j = 0; j < 12; j++) s += v[j] * eHat[e * D_DIM + lane + 64 * j];
    for (int o = 32; o; o >>= 1) s += __shfl_xor(s, o);
    d[e] = s;
  }
  if (lane == 0) {
    float rn = 1.f / fmaxf(sqrtf(ss), 1e-12f);
    float sc[NEXP], mx = -1e30f;
    for (int e = 0; e < NEXP; e++) {
      sc[e] = d[e] * rn + bias[t * NEXP + e];
      mx = fmaxf(mx, sc[e]);
    }
    float p[NEXP], sum = 0.f;
    for (int e = 0; e < NEXP; e++) {
      p[e] = expf(sc[e] - mx);
      sum += p[e];
    }
    float inv = 1.f / sum;
    int i1 = 0;
    for (int e = 1; e < NEXP; e++)
      if (sc[e] > sc[i1]) i1 = e;
    int i2 = -1;
    for (int e = 0; e < NEXP; e++) {
      if (e == i1) continue;
      if (i2 < 0 || sc[e] > sc[i2]) i2 = e;
    }
    gidx[t * 2] = i1;
    gidx[t * 2 + 1] = i2;
    gval[t * 2] = p[i1] * inv;
    gval[t * 2 + 1] = p[i2] * inv;
    atomicAdd(&counts[i1], 1);
    atomicAdd(&counts[i2], 1);
  }
}

// ---------------- segment bookkeeping ----------------

__global__ void scan_build(const int* __restrict__ counts, int* __restrict__ segstart,
                           int* __restrict__ cursors, int* __restrict__ tiles,
                           int* __restrict__ numtiles) {
  if (threadIdx.x == 0) {
    int off = 0;
    for (int e = 0; e < NEXP; e++) {
      segstart[e] = off;
      cursors[e] = off;
      off += counts[e];
    }
    segstart[NEXP] = off;              // == 2T
    segstart[NEXP + 1] = off + T_TOK;  // end of shared segment
    int nt = 0;
    for (int e = 0; e < NEXP + 1; e++) {
      int cnt = (e < NEXP) ? counts[e] : T_TOK;
      int ntl = (cnt + 127) >> 7;
      for (int l = 0; l < ntl; l++) {
        tiles[nt * 2] = e;
        tiles[nt * 2 + 1] = l;
        nt++;
      }
    }
    *numtiles = nt;
  }
}

__global__ void fill_assign(const int* __restrict__ gidx, int* __restrict__ cursors,
                            int* __restrict__ rowtok, int* __restrict__ slot_of) {
  int t = blockIdx.x * 256 + threadIdx.x;
  if (t >= T_TOK) return;
  for (int k = 0; k < 2; k++) {
    int e = gidx[t * 2 + k];
    int pos = atomicAdd(&cursors[e], 1);
    rowtok[pos] = t;
    slot_of[t * 2 + k] = pos;
  }
  rowtok[2 * T_TOK + t] = t;  // shared segment: identity
}

// ---------------- grouped FFN GEMM 1: h = gelu(Xg @ W1 + b1) ----------------

__global__ __launch_bounds__(256) void gemm_ffn1(
    const bf16* __restrict__ pHi, const bf16* __restrict__ W1T,
    const bf16* __restrict__ sW1T, const float* __restrict__ b1,
    const float* __restrict__ sb1, const int* __restrict__ segstart,
    const int* __restrict__ tiles, const int* __restrict__ numtiles,
    const int* __restrict__ rowtok, bf16* __restrict__ hbuf) {
  int gx = blockIdx.x;
  if (gx >= *numtiles) return;
  int seg = tiles[gx * 2], lt = tiles[gx * 2 + 1];
  int s0 = segstart[seg] + lt * 128;
  int send = segstart[seg + 1];
  const bf16* Bw = (seg < NEXP) ? W1T + (size_t)seg * H_DIM * D_DIM : sW1T;
  const float* bb = (seg < NEXP) ? b1 + seg * H_DIM : sb1;

  __shared__ __align__(16) bf16 As[128 * 32];
  __shared__ __align__(16) bf16 Bs[128 * 32];
  int tid = threadIdx.x, wave = tid >> 6, lane = tid & 63;
  int wr = wave >> 1, wc = wave & 1;
  int colbase = blockIdx.y * 128;
  int sc8 = (lane & 3) * 8;

  const bf16* arow[2];
  for (int p = 0; p < 2; p++) {
    int s = s0 + wave * 32 + p * 16 + (lane >> 2);
    if (s > send - 1) s = send - 1;
    arow[p] = pHi + (size_t)rowtok[s] * D_DIM;
  }

  f32x4 acc[4][4];
  for (int m = 0; m < 4; m++)
    for (int n = 0; n < 4; n++) acc[m][n] = 0.f;

  for (int ks = 0; ks < 24; ks++) {
    int kk = ks * 32;
    __syncthreads();
    for (int p = 0; p < 2; p++) {
      int r = wave * 32 + p * 16 + (lane >> 2);
      async16(&As[(wave * 32 + p * 16) * 32], arow[p] + kk + sc8);
      async16(&Bs[(wave * 32 + p * 16) * 32], Bw + (size_t)(colbase + r) * D_DIM + kk + sc8);
    }
    __syncthreads();
    int koff = (lane >> 4) * 8;
    short8 af[4], bfr[4];
    for (int m = 0; m < 4; m++)
      af[m] = *(const short8*)&As[(wr * 64 + m * 16 + (lane & 15)) * 32 + koff];
    for (int n = 0; n < 4; n++)
      bfr[n] = *(const short8*)&Bs[(wc * 64 + n * 16 + (lane & 15)) * 32 + koff];
    for (int m = 0; m < 4; m++)
      for (int n = 0; n < 4; n++)
        acc[m][n] = __builtin_amdgcn_mfma_f32_16x16x32_bf16(af[m], bfr[n], acc[m][n], 0, 0, 0);
  }
  for (int n = 0; n < 4; n++) {
    int c = colbase + wc * 64 + n * 16 + (lane & 15);
    float bv = bb[c];
    for (int m = 0; m < 4; m++)
      for (int j = 0; j < 4; j++) {
        int s = s0 + wr * 64 + m * 16 + (lane >> 4) * 4 + j;
        if (s < send) {
          float xv = acc[m][n][j] + bv;
          float g = 0.5f * xv * (1.f + erff(xv * 0.70710678118654752f));
          hbuf[(size_t)s * H_DIM + c] = __float2bfloat16(g);
        }
      }
  }
}

// ---------------- grouped FFN GEMM 2: eo = h @ W2 + b2 ----------------

__global__ __launch_bounds__(256) void gemm_ffn2(
    const bf16* __restrict__ hbuf, const bf16* __restrict__ W2T,
    const bf16* __restrict__ sW2T, const float* __restrict__ b2,
    const float* __restrict__ sb2, const int* __restrict__ segstart,
    const int* __restrict__ tiles, const int* __restrict__ numtiles,
    float* __restrict__ moebuf) {
  int gx = blockIdx.x;
  if (gx >= *numtiles) return;
  int seg = tiles[gx * 2], lt = tiles[gx * 2 + 1];
  int s0 = segstart[seg] + lt * 128;
  int send = segstart[seg + 1];
  const bf16* Bw = (seg < NEXP) ? W2T + (size_t)seg * H_DIM * D_DIM : sW2T;
  const float* bb = (seg < NEXP) ? b2 + seg * D_DIM : sb2;

  __shared__ __align__(16) bf16 As[128 * 32];
  __shared__ __align__(16) bf16 Bs[128 * 32];
  int tid = threadIdx.x, wave = tid >> 6, lane = tid & 63;
  int wr = wave >> 1, wc = wave & 1;
  int colbase = blockIdx.y * 128;
  int sc8 = (lane & 3) * 8;

  f32x4 acc[4][4];
  for (int m = 0; m < 4; m++)
    for (int n = 0; n < 4; n++) acc[m][n] = 0.f;

  for (int ks = 0; ks < 96; ks++) {
    int kk = ks * 32;
    __syncthreads();
    for (int p = 0; p < 2; p++) {
      int r = wave * 32 + p * 16 + (lane >> 2);
      async16(&As[(wave * 32 + p * 16) * 32], hbuf + (size_t)(s0 + r) * H_DIM + kk + sc8);
      async16(&Bs[(wave * 32 + p * 16) * 32], Bw + (size_t)(colbase + r) * H_DIM + kk + sc8);
    }
    __syncthreads();
    int koff = (lane >> 4) * 8;
    short8 af[4], bfr[4];
    for (int m = 0; m < 4; m++)
      af[m] = *(const short8*)&As[(wr * 64 + m * 16 + (lane & 15)) * 32 + koff];
    for (int n = 0; n < 4; n++)
      bfr[n] = *(const short8*)&Bs[(wc * 64 + n * 16 + (lane & 15)) * 32 + koff];
    for (int m = 0; m < 4; m++)
      for (int n = 0; n < 4; n++)
        acc[m][n] = __builtin_amdgcn_mfma_f32_16x16x32_bf16(af[m], bfr[n], acc[m][n], 0, 0, 0);
  }
  for (int n = 0; n < 4; n++) {
    int c = colbase + wc * 64 + n * 16 + (lane & 15);
    float bv = bb[c];
    for (int m = 0; m < 4; m++)
      for (int j = 0; j < 4; j++) {
        int s = s0 + wr * 64 + m * 16 + (lane >> 4) * 4 + j;
        if (s < send) moebuf[(size_t)s * D_DIM + c] = acc[m][n][j] + bv;
      }
  }
}

// ---------------- final combine ----------------

__global__ void combine_out(const float* __restrict__ moebuf, const float* __restrict__ gval,
                            const int* __restrict__ slot_of, float* __restrict__ out) {
  int i = blockIdx.x * 256 + threadIdx.x;
  const int total = T_TOK * (D_DIM / 4);
  if (i >= total) return;
  int t = i / (D_DIM / 4), c = i % (D_DIM / 4);
  float g0 = gval[2 * t], g1 = gval[2 * t + 1];
  int sA = slot_of[2 * t], sB = slot_of[2 * t + 1];
  const f32x4* pa = (const f32x4*)(moebuf + (size_t)sA * D_DIM) + c;
  const f32x4* pb = (const f32x4*)(moebuf + (size_t)sB * D_DIM) + c;
  const f32x4* ps = (const f32x4*)(moebuf + (size_t)(2 * T_TOK + t) * D_DIM) + c;
  f32x4 r = g0 * (*pa) + g1 * (*pb) + *ps;
  ((f32x4*)out)[i] = r;
}

// ---------------- host launch ----------------

extern "C" void kernel_launch(void* const* d_in, const int* in_sizes, int n_in,
                              void* d_out, int out_size, void* d_ws, size_t ws_size,
                              hipStream_t stream) {
  const float* x = (const float*)d_in[0];
  const float* Wlinear = (const float*)d_in[1];
  const float* learnedE = (const float*)d_in[2];
  const float* bias = (const float*)d_in[3];
  const float* W1 = (const float*)d_in[4];
  const float* b1 = (const float*)d_in[5];
  const float* W2 = (const float*)d_in[6];
  const float* b2 = (const float*)d_in[7];
  const float* sW1 = (const float*)d_in[8];
  const float* sb1 = (const float*)d_in[9];
  const float* sW2 = (const float*)d_in[10];
  const float* sb2 = (const float*)d_in[11];
  float* out = (float*)d_out;

  char* ws = (char*)d_ws;
  size_t off = 0;
  auto alloc = [&](size_t bytes) {
    char* p = ws + off;
    off += (bytes + 255) & ~(size_t)255;
    return p;
  };
  float* eHat = (float*)alloc(8 * 768 * 4);
  bf16* pHi = (bf16*)alloc((size_t)T_TOK * D_DIM * 2);
  bf16* pLo = (bf16*)alloc((size_t)T_TOK * D_DIM * 2);
  bf16* wHi = (bf16*)alloc((size_t)D_DIM * D_DIM * 2);
  bf16* wLo = (bf16*)alloc((size_t)D_DIM * D_DIM * 2);
  bf16* W1T = (bf16*)alloc((size_t)NEXP * D_DIM * H_DIM * 2);
  bf16* W2T = (bf16*)alloc((size_t)NEXP * D_DIM * H_DIM * 2);
  bf16* sW1T = (bf16*)alloc((size_t)D_DIM * H_DIM * 2);
  bf16* sW2T = (bf16*)alloc((size_t)D_DIM * H_DIM * 2);
  float* y = (float*)alloc((size_t)T_TOK * D_DIM * 4);
  bf16* hbuf = (bf16*)alloc((size_t)3 * T_TOK * H_DIM * 2);
  float* moebuf = (float*)alloc((size_t)3 * T_TOK * D_DIM * 4);
  int* gidx = (int*)alloc(T_TOK * 2 * 4);
  float* gval = (float*)alloc(T_TOK * 2 * 4);
  int* rowtok = (int*)alloc(3 * T_TOK * 4);
  int* slot_of = (int*)alloc(T_TOK * 2 * 4);
  int* counts = (int*)alloc(8 * 4);
  int* segstart = (int*)alloc(10 * 4);
  int* cursors = (int*)alloc(8 * 4);
  int* numtiles = (int*)alloc(4);
  int* tiles = (int*)alloc(MAXTILES * 2 * 4);
  (void)ws_size; (void)in_sizes; (void)n_in; (void)out_size;

  hipMemsetAsync(counts, 0, 8 * 4, stream);
  norm_learnedE<<<1, 256, 0, stream>>>(learnedE, eHat);
  cast_hilo<<<2048, 256, 0, stream>>>(x, pHi, pLo, T_TOK * D_DIM);
  cast_hilo<<<1024, 256, 0, stream>>>(Wlinear, wHi, wLo, D_DIM * D_DIM);
  transpose_cast<<<dim3(D_DIM / 32, H_DIM / 32, NEXP), 256, 0, stream>>>(W1, W1T, D_DIM, H_DIM);
  transpose_cast<<<dim3(H_DIM / 32, D_DIM / 32, NEXP), 256, 0, stream>>>(W2, W2T, H_DIM, D_DIM);
  transpose_cast<<<dim3(D_DIM / 32, H_DIM / 32, 1), 256, 0, stream>>>(sW1, sW1T, D_DIM, H_DIM);
  transpose_cast<<<dim3(H_DIM / 32, D_DIM / 32, 1), 256, 0, stream>>>(sW2, sW2T, H_DIM, D_DIM);

  gemm_router<<<dim3(T_TOK / 128, D_DIM / 128), 256, 0, stream>>>(pHi, pLo, wHi, wLo, y);
  router_epi<<<T_TOK / 4, 256, 0, stream>>>(y, eHat, bias, gidx, gval, counts);
  scan_build<<<1, 64, 0, stream>>>(counts, segstart, cursors, tiles, numtiles);
  fill_assign<<<(T_TOK + 255) / 256, 256, 0, stream>>>(gidx, cursors, rowtok, slot_of);

  gemm_ffn1<<<dim3(MAXTILES, H_DIM / 128), 256, 0, stream>>>(
      pHi, W1T, sW1T, b1, sb1, segstart, tiles, numtiles, rowtok, hbuf);
  gemm_ffn2<<<dim3(MAXTILES, D_DIM / 128), 256, 0, stream>>>(
      hbuf, W2T, sW2T, b2, sb2, segstart, tiles, numtiles, moebuf);

  combine_out<<<(T_TOK * (D_DIM / 4) + 255) / 256, 256, 0, stream>>>(moebuf, gval, slot_of, out);
}